// Round 2
// baseline (114.331 us; speedup 1.0000x reference)
//
#include <hip/hip_runtime.h>

// Ball query: for each query point, collect up to K=64 key indices (in key
// order) with squared distance < R2; pad remaining slots with the first hit
// index (0 if no hits).  B=4, N1=2048, N2=8192.
//
// One 64-lane wave per query. Keys are first transposed to SoA in d_ws so the
// scan loop issues 3 perfectly-coalesced dword loads per 64-key chunk. The
// scan body is branch-free (ballot + mbcnt prefix + predicated store) and has
// no early exit (expected hits ~34 < K), so loads pipeline across the
// unrolled iterations.

constexpr int   K    = 64;
constexpr float R2   = 0.01f;   // 0.1^2
constexpr int   B    = 4;
constexpr int   N1   = 2048;
constexpr int   N2   = 8192;

__global__ __launch_bounds__(256) void transpose_keys_kernel(
    const float* __restrict__ key,   // [B*N2, 3] AoS
    float* __restrict__ soa)         // [3, B*N2] SoA
{
    const int p = blockIdx.x * blockDim.x + threadIdx.x;   // 0 .. B*N2-1
    if (p < B * N2) {
        const float x = key[p * 3 + 0];
        const float y = key[p * 3 + 1];
        const float z = key[p * 3 + 2];
        soa[p]             = x;
        soa[B * N2 + p]    = y;
        soa[2 * B * N2 + p] = z;
    }
}

template <bool SOA>
__global__ __launch_bounds__(256) void ballquery_kernel(
    const float* __restrict__ query,   // [B, N1, 3]
    const float* __restrict__ keys,    // SOA ? [3, B*N2] : [B*N2, 3]
    int* __restrict__ out)             // [B, N1, K]
{
    const int lane = threadIdx.x & 63;
    const int q = blockIdx.x * (blockDim.x >> 6) + (threadIdx.x >> 6);  // 0 .. B*N1-1
    const int b = q >> 11;             // q / N1  (N1 = 2048)

    const float qx = query[q * 3 + 0];
    const float qy = query[q * 3 + 1];
    const float qz = query[q * 3 + 2];

    const int bofs = b * N2;
    int* op = out + (size_t)q * K;

    int count = 0;       // wave-uniform
    int first = 0;       // first hit index; 0 if none (matches argmax of all-false)

    #pragma unroll 8
    for (int c = 0; c < N2 / 64; ++c) {
        const int j = (c << 6) + lane;
        float kx, ky, kz;
        if (SOA) {
            kx = keys[bofs + j];
            ky = keys[B * N2 + bofs + j];
            kz = keys[2 * B * N2 + bofs + j];
        } else {
            const float* kp = keys + (size_t)(bofs + j) * 3;
            kx = kp[0]; ky = kp[1]; kz = kp[2];
        }
        const float dx = kx - qx;
        const float dy = ky - qy;
        const float dz = kz - qz;
        const bool within = dx * dx + dy * dy + dz * dz < R2;

        const unsigned long long mask = __ballot(within);

        // First hit: only possible while count==0. Scalar select, no branch.
        first = (count == 0 && mask) ? ((c << 6) + (int)__builtin_ctzll(mask))
                                     : first;

        // Prefix popcount of mask below this lane (v_mbcnt pair).
        const int prefix = (int)__builtin_amdgcn_mbcnt_hi(
            (unsigned)(mask >> 32),
            __builtin_amdgcn_mbcnt_lo((unsigned)mask, 0u));
        const int slot = count + prefix;
        if (within && slot < K) op[slot] = j;   // predicated scattered store

        count += (int)__popcll(mask);
    }

    // Pad unfilled slots with `first`.
    const int cnt = count < K ? count : K;
    const int s = cnt + lane;
    if (s < K) op[s] = first;
}

extern "C" void kernel_launch(void* const* d_in, const int* in_sizes, int n_in,
                              void* d_out, int out_size, void* d_ws, size_t ws_size,
                              hipStream_t stream) {
    const float* query = (const float*)d_in[0];   // B*N1*3 floats
    const float* key   = (const float*)d_in[1];   // B*N2*3 floats
    int* out = (int*)d_out;                       // B*N1*K int32

    const int total_queries = B * N1;             // 8192 waves
    const int waves_per_block = 4;                // 256 threads
    const int blocks = total_queries / waves_per_block;  // 2048

    const size_t soa_bytes = (size_t)3 * B * N2 * sizeof(float);  // 393 KB
    if (ws_size >= soa_bytes) {
        float* soa = (float*)d_ws;
        transpose_keys_kernel<<<(B * N2 + 255) / 256, 256, 0, stream>>>(key, soa);
        ballquery_kernel<true><<<blocks, waves_per_block * 64, 0, stream>>>(query, soa, out);
    } else {
        ballquery_kernel<false><<<blocks, waves_per_block * 64, 0, stream>>>(query, key, out);
    }
}

// Round 3
// 84.548 us; speedup vs baseline: 1.3523x; 1.3523x over previous
//
#include <hip/hip_runtime.h>

// Ball query via 5x5x5 uniform grid + counting sort + per-wave hit bitmap.
// B=4, N1=2048 queries, N2=8192 keys, K=64, r=0.1 (cell = 0.2 = 2r, so a
// query ball overlaps at most a 2x2x2 octant of cells).
//
// Pipeline (all on `stream`):
//   1. zero_kernel     : zero histogram + scatter cursors in d_ws
//   2. hist_kernel     : per-batch 125-cell histogram (global atomics)
//   3. scan_kernel     : exclusive prefix sum -> cell_start[B][126]
//   4. scatter_kernel  : keys -> sorted[B][N2] float4{x,y,z,idx} grouped by cell
//   5. ballquery_grid  : one wave per query; scan 4 contiguous column-runs,
//                        set bits in an 8192-bit LDS bitmap keyed by original
//                        index, then extract first K set bits in order.
//
// The bitmap makes output order exact with no sorting, even if >K hits.

constexpr int   K    = 64;
constexpr float R2   = 0.01f;   // 0.1^2
constexpr int   B    = 4;
constexpr int   N1   = 2048;
constexpr int   N2   = 8192;
constexpr int   GC   = 5;                 // grid cells per dim
constexpr int   NCELL = GC * GC * GC;     // 125
constexpr float INVCELL = 5.0f;           // 1 / 0.2

// ---------------- workspace layout ----------------
// [0, 512KB)            : sorted float4 [B*N2]
// [512KB, +500 ints)    : counts   [B*NCELL]
// next 500 ints         : counters [B*NCELL]
// next 504 ints         : cell_start [B*(NCELL+1)]
constexpr size_t SORTED_BYTES = (size_t)B * N2 * 16;
constexpr size_t WS_NEEDED    = SORTED_BYTES + (size_t)(B * NCELL * 2 + B * (NCELL + 1)) * 4;

__device__ __forceinline__ int cell_of(float v) {
    int c = (int)(v * INVCELL);
    return c < 0 ? 0 : (c > GC - 1 ? GC - 1 : c);
}

__global__ __launch_bounds__(256) void zero_kernel(int* __restrict__ z, int n) {
    for (int i = threadIdx.x; i < n; i += 256) z[i] = 0;
}

__global__ __launch_bounds__(256) void hist_kernel(
    const float* __restrict__ key, int* __restrict__ counts)
{
    const int p = blockIdx.x * 256 + threadIdx.x;       // 0 .. B*N2-1
    const int b = p >> 13;
    const float x = key[p * 3 + 0];
    const float y = key[p * 3 + 1];
    const float z = key[p * 3 + 2];
    const int cell = (cell_of(x) * GC + cell_of(y)) * GC + cell_of(z);
    atomicAdd(&counts[b * NCELL + cell], 1);
}

__global__ __launch_bounds__(128) void scan_kernel(
    const int* __restrict__ counts, int* __restrict__ cell_start)
{
    __shared__ int sbuf[128];
    const int t = threadIdx.x;
    const int b = blockIdx.x;
    int v = (t < NCELL) ? counts[b * NCELL + t] : 0;
    sbuf[t] = v;
    __syncthreads();
    for (int off = 1; off < 128; off <<= 1) {
        int x = (t >= off) ? sbuf[t - off] : 0;
        __syncthreads();
        sbuf[t] += x;
        __syncthreads();
    }
    if (t < NCELL) cell_start[b * (NCELL + 1) + t + 1] = sbuf[t];
    if (t == 0)    cell_start[b * (NCELL + 1)] = 0;
}

__global__ __launch_bounds__(256) void scatter_kernel(
    const float* __restrict__ key, const int* __restrict__ cell_start,
    int* __restrict__ counters, float4* __restrict__ sorted)
{
    const int p = blockIdx.x * 256 + threadIdx.x;       // 0 .. B*N2-1
    const int b = p >> 13;
    const int i = p & (N2 - 1);
    const float x = key[p * 3 + 0];
    const float y = key[p * 3 + 1];
    const float z = key[p * 3 + 2];
    const int cell = (cell_of(x) * GC + cell_of(y)) * GC + cell_of(z);
    const int ofs  = atomicAdd(&counters[b * NCELL + cell], 1);
    const int pos  = cell_start[b * (NCELL + 1) + cell] + ofs;
    float4 v;
    v.x = x; v.y = y; v.z = z; v.w = __int_as_float(i);
    sorted[b * N2 + pos] = v;
}

__global__ __launch_bounds__(256) void ballquery_grid_kernel(
    const float* __restrict__ query,        // [B*N1, 3]
    const float4* __restrict__ sorted,      // [B*N2] grouped by cell
    const int* __restrict__ cell_start,     // [B, 126]
    int* __restrict__ out)                  // [B*N1, K]
{
    __shared__ unsigned int bm[4 * 256];    // 4 waves x 8192-bit bitmap

    const int lane = threadIdx.x & 63;
    const int wv   = threadIdx.x >> 6;
    const int q    = blockIdx.x * 4 + wv;   // 0 .. B*N1-1
    const int b    = q >> 11;

    const float qx = query[q * 3 + 0];
    const float qy = query[q * 3 + 1];
    const float qz = query[q * 3 + 2];

    // Octant of cells the ball can touch (cell = 2r, so +/-1 on the near side).
    const float ux = qx * INVCELL, uy = qy * INVCELL, uz = qz * INVCELL;
    const int cx = cell_of(qx), cy = cell_of(qy), cz = cell_of(qz);
    const int nx = (ux - cx < 0.5f) ? cx - 1 : cx + 1;
    const int ny = (uy - cy < 0.5f) ? cy - 1 : cy + 1;
    const int nz = (uz - cz < 0.5f) ? cz - 1 : cz + 1;
    const int xlo = max(0, min(cx, nx)), xhi = min(GC - 1, max(cx, nx));
    const int ylo = max(0, min(cy, ny)), yhi = min(GC - 1, max(cy, ny));
    const int zlo = max(0, min(cz, nz)), zhi = min(GC - 1, max(cz, nz));

    unsigned int* wbm = bm + wv * 256;
    // clear my wave's bitmap (ds_write_b128, stride-1 lanes)
    uint4 zz; zz.x = zz.y = zz.z = zz.w = 0u;
    ((uint4*)wbm)[lane] = zz;
    __threadfence_block();

    const int*    cs = cell_start + b * (NCELL + 1);
    const float4* sb = sorted + b * N2;

    for (int xx = xlo; xx <= xhi; ++xx) {
        for (int yy = ylo; yy <= yhi; ++yy) {
            const int colz = (xx * GC + yy) * GC;
            const int s = cs[colz + zlo];
            const int e = cs[colz + zhi + 1];          // z-cells are contiguous
            for (int t0 = s; t0 < e; t0 += 64) {
                const int i = t0 + lane;
                const float4 kv = sb[min(i, e - 1)];
                const float dx = kv.x - qx;
                const float dy = kv.y - qy;
                const float dz = kv.z - qz;
                const bool within = (i < e) && (dx * dx + dy * dy + dz * dz < R2);
                if (within) {
                    const int id = __float_as_int(kv.w);
                    atomicOr(&wbm[id >> 5], 1u << (id & 31));
                }
            }
        }
    }
    __threadfence_block();

    // ---- extraction: lane owns original-index range [128*lane, 128*lane+128)
    const uint4 w = ((const uint4*)wbm)[lane];
    const int c = __popc(w.x) + __popc(w.y) + __popc(w.z) + __popc(w.w);

    // inclusive wave prefix sum of c
    int x = c;
    #pragma unroll
    for (int off = 1; off < 64; off <<= 1) {
        int y = __shfl_up(x, off);
        if (lane >= off) x += y;
    }
    const int base = x - c;
    const int cnt  = __shfl(x, 63);

    // first set bit overall (0 if none)
    int fs;
    if      (w.x) fs = __builtin_ctz(w.x);
    else if (w.y) fs = 32 + __builtin_ctz(w.y);
    else if (w.z) fs = 64 + __builtin_ctz(w.z);
    else if (w.w) fs = 96 + __builtin_ctz(w.w);
    else          fs = 0;
    int myfirst = c ? (lane << 7) + fs : 0x7fffffff;
    #pragma unroll
    for (int off = 32; off; off >>= 1)
        myfirst = min(myfirst, __shfl_xor(myfirst, off));
    const int firstIdx = (cnt == 0) ? 0 : myfirst;

    // emit set bits in order
    int* op = out + q * K;
    int slot = base;
    unsigned int wr[4] = {w.x, w.y, w.z, w.w};
    #pragma unroll
    for (int r = 0; r < 4; ++r) {
        unsigned int m = wr[r];
        const int bb = (lane << 7) + (r << 5);
        while (m) {
            const int bp = __builtin_ctz(m);
            m &= m - 1;
            if (slot < K) op[slot] = bb + bp;
            ++slot;
        }
    }

    // pad remaining slots with firstIdx
    const int kpad = cnt < K ? cnt : K;
    const int s2 = kpad + lane;
    if (s2 < K) op[s2] = firstIdx;
}

// ---------------- fallback (ws too small): v1 brute force ----------------
__global__ __launch_bounds__(256) void ballquery_bruteforce_kernel(
    const float* __restrict__ query, const float* __restrict__ key,
    int* __restrict__ out)
{
    const int lane = threadIdx.x & 63;
    const int q = blockIdx.x * 4 + (threadIdx.x >> 6);
    const int b = q >> 11;
    const float qx = query[q * 3], qy = query[q * 3 + 1], qz = query[q * 3 + 2];
    const float* kb = key + (size_t)b * N2 * 3;
    int* op = out + (size_t)q * K;
    int count = 0, first = 0;
    bool have_first = false;
    const unsigned long long lane_mask_lt = (lane == 0) ? 0ull : (~0ull >> (64 - lane));
    for (int c = 0; c < N2 / 64; ++c) {
        if (count >= K) break;
        const int j = (c << 6) + lane;
        const float* kp = kb + j * 3;
        const float dx = kp[0] - qx, dy = kp[1] - qy, dz = kp[2] - qz;
        const bool within = dx * dx + dy * dy + dz * dz < R2;
        const unsigned long long mask = __ballot(within);
        if (mask) {
            if (!have_first) { first = (c << 6) + __builtin_ctzll(mask); have_first = true; }
            if (within) {
                const int slot = count + __popcll(mask & lane_mask_lt);
                if (slot < K) op[slot] = j;
            }
            count += __popcll(mask);
        }
    }
    const int cnt = count < K ? count : K;
    if (cnt + lane < K) op[cnt + lane] = first;
}

extern "C" void kernel_launch(void* const* d_in, const int* in_sizes, int n_in,
                              void* d_out, int out_size, void* d_ws, size_t ws_size,
                              hipStream_t stream) {
    const float* query = (const float*)d_in[0];   // B*N1*3 floats
    const float* key   = (const float*)d_in[1];   // B*N2*3 floats
    int* out = (int*)d_out;                       // B*N1*K int32

    if (ws_size < WS_NEEDED) {
        ballquery_bruteforce_kernel<<<(B * N1) / 4, 256, 0, stream>>>(query, key, out);
        return;
    }

    float4* sorted     = (float4*)d_ws;
    int*    counts     = (int*)((char*)d_ws + SORTED_BYTES);
    int*    counters   = counts + B * NCELL;
    int*    cell_start = counters + B * NCELL;

    zero_kernel<<<1, 256, 0, stream>>>(counts, B * NCELL * 2);
    hist_kernel<<<(B * N2) / 256, 256, 0, stream>>>(key, counts);
    scan_kernel<<<B, 128, 0, stream>>>(counts, cell_start);
    scatter_kernel<<<(B * N2) / 256, 256, 0, stream>>>(key, cell_start, counters, sorted);
    ballquery_grid_kernel<<<(B * N1) / 4, 256, 0, stream>>>(query, sorted, cell_start, out);
}

// Round 4
// 74.396 us; speedup vs baseline: 1.5368x; 1.1365x over previous
//
#include <hip/hip_runtime.h>

// Ball query via 5x5x5 uniform grid + counting sort + per-wave hit bitmap.
// B=4, N1=2048 queries, N2=8192 keys, K=64, r=0.1 (cell = 0.2 = 2r, so a
// query ball overlaps at most a 2x2x2 octant of cells).
//
// Two kernel nodes only (launch/dependency overhead dominated the R3 graph):
//   1. build_kernel : one block per batch (1024 thr). LDS histogram ->
//                     LDS prefix scan -> LDS-cursor scatter. Produces
//                     sorted[B][N2] float4{x,y,z,idx} grouped by cell and
//                     cell_start[B][126].
//   2. ballquery_grid_kernel : one wave per query; scans <=4 contiguous
//                     (x,y)-column z-runs, sets bits in an 8192-bit LDS
//                     bitmap keyed by ORIGINAL key index, then extracts the
//                     first K set bits in order (exact key-order output with
//                     no sort, even when >K hits).

constexpr int   K    = 64;
constexpr float R2   = 0.01f;   // 0.1^2
constexpr int   B    = 4;
constexpr int   N1   = 2048;
constexpr int   N2   = 8192;
constexpr int   GC   = 5;                 // grid cells per dim
constexpr int   NCELL = GC * GC * GC;     // 125
constexpr float INVCELL = 5.0f;           // 1 / 0.2

// ---------------- workspace layout ----------------
// [0, 512KB)   : sorted float4 [B*N2]
// then         : cell_start [B*(NCELL+1)] ints
constexpr size_t SORTED_BYTES = (size_t)B * N2 * 16;
constexpr size_t WS_NEEDED    = SORTED_BYTES + (size_t)(B * (NCELL + 1)) * 4;

__device__ __forceinline__ int cell_of(float v) {
    int c = (int)(v * INVCELL);
    return c < 0 ? 0 : (c > GC - 1 ? GC - 1 : c);
}

// ---------------- fused counting-sort build: 1 block per batch ----------------
__global__ __launch_bounds__(1024) void build_kernel(
    const float* __restrict__ key,        // [B*N2, 3]
    float4* __restrict__ sorted,          // [B*N2]
    int* __restrict__ cell_start)         // [B, 126]
{
    __shared__ int hist[NCELL];           // counts, then scatter cursors
    __shared__ int sbuf[128];             // scan buffer
    __shared__ int start[NCELL + 1];

    const int b = blockIdx.x;
    const int t = threadIdx.x;
    constexpr int PER = N2 / 1024;        // 8 keys per thread

    if (t < NCELL) hist[t] = 0;
    __syncthreads();

    const float* kb = key + (size_t)b * N2 * 3;
    int mycell[PER];
    #pragma unroll
    for (int r = 0; r < PER; ++r) {
        const int i = r * 1024 + t;
        const float x = kb[i * 3 + 0];
        const float y = kb[i * 3 + 1];
        const float z = kb[i * 3 + 2];
        const int cell = (cell_of(x) * GC + cell_of(y)) * GC + cell_of(z);
        mycell[r] = cell;
        atomicAdd(&hist[cell], 1);
    }
    __syncthreads();

    // Hillis-Steele inclusive scan over 128 slots (threads 0-127 active,
    // barriers unconditional for the whole block).
    if (t < 128) sbuf[t] = (t < NCELL) ? hist[t] : 0;
    __syncthreads();
    for (int off = 1; off < 128; off <<= 1) {
        int v = 0;
        if (t < 128 && t >= off) v = sbuf[t - off];
        __syncthreads();
        if (t < 128) sbuf[t] += v;
        __syncthreads();
    }
    if (t < NCELL) start[t + 1] = sbuf[t];
    if (t == 0)    start[0] = 0;
    __syncthreads();
    if (t < NCELL + 1) cell_start[b * (NCELL + 1) + t] = start[t];
    if (t < NCELL)     hist[t] = start[t];          // reset as cursors
    __syncthreads();

    float4* sb = sorted + (size_t)b * N2;
    #pragma unroll
    for (int r = 0; r < PER; ++r) {
        const int i = r * 1024 + t;
        const int cell = mycell[r];
        const int pos = atomicAdd(&hist[cell], 1);  // within-cell order arbitrary;
                                                    // bitmap restores key order
        float4 v;
        v.x = kb[i * 3 + 0];                        // L1/L2-hot reload
        v.y = kb[i * 3 + 1];
        v.z = kb[i * 3 + 2];
        v.w = __int_as_float(i);
        sb[pos] = v;
    }
}

// ---------------- per-query grid scan ----------------
__global__ __launch_bounds__(256) void ballquery_grid_kernel(
    const float* __restrict__ query,        // [B*N1, 3]
    const float4* __restrict__ sorted,      // [B*N2] grouped by cell
    const int* __restrict__ cell_start,     // [B, 126]
    int* __restrict__ out)                  // [B*N1, K]
{
    __shared__ unsigned int bm[4 * 256];    // 4 waves x 8192-bit bitmap

    const int lane = threadIdx.x & 63;
    const int wv   = threadIdx.x >> 6;
    const int q    = blockIdx.x * 4 + wv;   // 0 .. B*N1-1
    const int b    = q >> 11;

    const float qx = query[q * 3 + 0];
    const float qy = query[q * 3 + 1];
    const float qz = query[q * 3 + 2];

    // Octant of cells the ball can touch (cell = 2r, so +/-1 on the near side).
    const float ux = qx * INVCELL, uy = qy * INVCELL, uz = qz * INVCELL;
    const int cx = cell_of(qx), cy = cell_of(qy), cz = cell_of(qz);
    const int nx = (ux - cx < 0.5f) ? cx - 1 : cx + 1;
    const int ny = (uy - cy < 0.5f) ? cy - 1 : cy + 1;
    const int nz = (uz - cz < 0.5f) ? cz - 1 : cz + 1;
    const int xlo = max(0, min(cx, nx)), xhi = min(GC - 1, max(cx, nx));
    const int ylo = max(0, min(cy, ny)), yhi = min(GC - 1, max(cy, ny));
    const int zlo = max(0, min(cz, nz)), zhi = min(GC - 1, max(cz, nz));

    unsigned int* wbm = bm + wv * 256;
    uint4 zz; zz.x = zz.y = zz.z = zz.w = 0u;
    ((uint4*)wbm)[lane] = zz;               // clear bitmap (ds_write_b128)
    __threadfence_block();

    const int*    cs = cell_start + b * (NCELL + 1);
    const float4* sb = sorted + (size_t)b * N2;

    for (int xx = xlo; xx <= xhi; ++xx) {
        for (int yy = ylo; yy <= yhi; ++yy) {
            const int colz = (xx * GC + yy) * GC;
            const int s = cs[colz + zlo];
            const int e = cs[colz + zhi + 1];          // z-cells are contiguous
            for (int t0 = s; t0 < e; t0 += 64) {
                const int i = t0 + lane;
                const float4 kv = sb[min(i, e - 1)];
                const float dx = kv.x - qx;
                const float dy = kv.y - qy;
                const float dz = kv.z - qz;
                const bool within = (i < e) && (dx * dx + dy * dy + dz * dz < R2);
                if (within) {
                    const int id = __float_as_int(kv.w);
                    atomicOr(&wbm[id >> 5], 1u << (id & 31));
                }
            }
        }
    }
    __threadfence_block();

    // ---- extraction: lane owns original-index range [128*lane, 128*lane+128)
    const uint4 w = ((const uint4*)wbm)[lane];
    const int c = __popc(w.x) + __popc(w.y) + __popc(w.z) + __popc(w.w);

    // inclusive wave prefix sum of c
    int x = c;
    #pragma unroll
    for (int off = 1; off < 64; off <<= 1) {
        int y = __shfl_up(x, off);
        if (lane >= off) x += y;
    }
    const int base = x - c;
    const int cnt  = __shfl(x, 63);

    // first set bit overall (0 if none)
    int fs;
    if      (w.x) fs = __builtin_ctz(w.x);
    else if (w.y) fs = 32 + __builtin_ctz(w.y);
    else if (w.z) fs = 64 + __builtin_ctz(w.z);
    else if (w.w) fs = 96 + __builtin_ctz(w.w);
    else          fs = 0;
    int myfirst = c ? (lane << 7) + fs : 0x7fffffff;
    #pragma unroll
    for (int off = 32; off; off >>= 1)
        myfirst = min(myfirst, __shfl_xor(myfirst, off));
    const int firstIdx = (cnt == 0) ? 0 : myfirst;

    // emit set bits in order
    int* op = out + q * K;
    int slot = base;
    unsigned int wr[4] = {w.x, w.y, w.z, w.w};
    #pragma unroll
    for (int r = 0; r < 4; ++r) {
        unsigned int m = wr[r];
        const int bb = (lane << 7) + (r << 5);
        while (m) {
            const int bp = __builtin_ctz(m);
            m &= m - 1;
            if (slot < K) op[slot] = bb + bp;
            ++slot;
        }
    }

    // pad remaining slots with firstIdx
    const int kpad = cnt < K ? cnt : K;
    const int s2 = kpad + lane;
    if (s2 < K) op[s2] = firstIdx;
}

// ---------------- fallback (ws too small): brute force ----------------
__global__ __launch_bounds__(256) void ballquery_bruteforce_kernel(
    const float* __restrict__ query, const float* __restrict__ key,
    int* __restrict__ out)
{
    const int lane = threadIdx.x & 63;
    const int q = blockIdx.x * 4 + (threadIdx.x >> 6);
    const int b = q >> 11;
    const float qx = query[q * 3], qy = query[q * 3 + 1], qz = query[q * 3 + 2];
    const float* kb = key + (size_t)b * N2 * 3;
    int* op = out + (size_t)q * K;
    int count = 0, first = 0;
    bool have_first = false;
    const unsigned long long lane_mask_lt = (lane == 0) ? 0ull : (~0ull >> (64 - lane));
    for (int c = 0; c < N2 / 64; ++c) {
        if (count >= K) break;
        const int j = (c << 6) + lane;
        const float* kp = kb + j * 3;
        const float dx = kp[0] - qx, dy = kp[1] - qy, dz = kp[2] - qz;
        const bool within = dx * dx + dy * dy + dz * dz < R2;
        const unsigned long long mask = __ballot(within);
        if (mask) {
            if (!have_first) { first = (c << 6) + __builtin_ctzll(mask); have_first = true; }
            if (within) {
                const int slot = count + __popcll(mask & lane_mask_lt);
                if (slot < K) op[slot] = j;
            }
            count += __popcll(mask);
        }
    }
    const int cnt = count < K ? count : K;
    if (cnt + lane < K) op[cnt + lane] = first;
}

extern "C" void kernel_launch(void* const* d_in, const int* in_sizes, int n_in,
                              void* d_out, int out_size, void* d_ws, size_t ws_size,
                              hipStream_t stream) {
    const float* query = (const float*)d_in[0];   // B*N1*3 floats
    const float* key   = (const float*)d_in[1];   // B*N2*3 floats
    int* out = (int*)d_out;                       // B*N1*K int32

    if (ws_size < WS_NEEDED) {
        ballquery_bruteforce_kernel<<<(B * N1) / 4, 256, 0, stream>>>(query, key, out);
        return;
    }

    float4* sorted     = (float4*)d_ws;
    int*    cell_start = (int*)((char*)d_ws + SORTED_BYTES);

    build_kernel<<<B, 1024, 0, stream>>>(key, sorted, cell_start);
    ballquery_grid_kernel<<<(B * N1) / 4, 256, 0, stream>>>(query, sorted, cell_start, out);
}

// Round 5
// 68.713 us; speedup vs baseline: 1.6639x; 1.0827x over previous
//
#include <hip/hip_runtime.h>

// Ball query via 5x5x5 uniform grid + parallel counting sort + per-wave hit
// bitmap. B=4, N1=2048 queries, N2=8192 keys, K=64, r=0.1 (cell = 0.2 = 2r,
// so a query ball overlaps at most a 2x2x2 octant of cells).
//
// Three kernel nodes (R4's 4-block build was the serial weak link; the
// counting sort is now 32x wider and deterministic with no global atomics):
//   1. hist_kernel    : 128 blocks x 256 thr; per-256-key-sub-block LDS
//                       histogram -> hists[128][125] (plain stores).
//   2. scatter_kernel : 128 blocks; each redundantly scans its batch's 32
//                       sub-histograms (L2-hot) to get cell starts + its own
//                       per-cell base, then scatters its 256 keys via LDS
//                       cursors into sorted[B][N2] float4{x,y,z,idx}.
//                       Per-(sub,cell) output ranges are disjoint => race-free.
//   3. ballquery_grid_kernel : one wave per query; scans <=4 contiguous
//                       (x,y)-column z-runs, sets bits in an 8192-bit LDS
//                       bitmap keyed by ORIGINAL key index, then extracts the
//                       first K set bits in order (exact key-order output, no
//                       sort needed, even when >K hits). Unchanged from R4.

constexpr int   K    = 64;
constexpr float R2   = 0.01f;   // 0.1^2
constexpr int   B    = 4;
constexpr int   N1   = 2048;
constexpr int   N2   = 8192;
constexpr int   GC   = 5;                 // grid cells per dim
constexpr int   NCELL = GC * GC * GC;     // 125
constexpr float INVCELL = 5.0f;           // 1 / 0.2
constexpr int   SUBS       = 128;         // 256-key sub-blocks total (B*N2/256)
constexpr int   SUBS_PER_B = 32;          // per batch

// ---------------- workspace layout ----------------
// [0, 512KB)   : sorted float4 [B*N2]
// then         : cell_start [B*(NCELL+1)] ints
// then         : hists [SUBS*NCELL] ints
constexpr size_t SORTED_BYTES = (size_t)B * N2 * 16;
constexpr size_t CS_BYTES     = (size_t)B * (NCELL + 1) * 4;
constexpr size_t WS_NEEDED    = SORTED_BYTES + CS_BYTES + (size_t)SUBS * NCELL * 4;

__device__ __forceinline__ int cell_of(float v) {
    int c = (int)(v * INVCELL);
    return c < 0 ? 0 : (c > GC - 1 ? GC - 1 : c);
}

// ---------------- pass 1: per-sub-block histograms ----------------
__global__ __launch_bounds__(256) void hist_kernel(
    const float* __restrict__ key,       // [B*N2, 3]
    int* __restrict__ hists)             // [SUBS, NCELL]
{
    __shared__ int h[NCELL];
    const int k = blockIdx.x;            // sub-block id 0..127
    const int t = threadIdx.x;
    if (t < NCELL) h[t] = 0;
    __syncthreads();
    const int p = k * 256 + t;           // global key id
    const float x = key[p * 3 + 0];
    const float y = key[p * 3 + 1];
    const float z = key[p * 3 + 2];
    const int cell = (cell_of(x) * GC + cell_of(y)) * GC + cell_of(z);
    atomicAdd(&h[cell], 1);
    __syncthreads();
    if (t < NCELL) hists[k * NCELL + t] = h[t];
}

// ---------------- pass 2: redundant scan + deterministic scatter ----------------
__global__ __launch_bounds__(256) void scatter_kernel(
    const float* __restrict__ key,       // [B*N2, 3]
    const int* __restrict__ hists,       // [SUBS, NCELL]
    int* __restrict__ cell_start,        // [B, NCELL+1]
    float4* __restrict__ sorted)         // [B*N2]
{
    __shared__ int sbuf[128];
    __shared__ int cursor[NCELL];

    const int k = blockIdx.x;            // sub-block id 0..127
    const int b = k >> 5;                // batch
    const int s = k & 31;                // sub index within batch
    const int t = threadIdx.x;

    // Thread t (< NCELL) owns cell t: accumulate this batch's 32 sub-hists,
    // capturing the prefix over sub-blocks before mine.
    int mybase = 0, total = 0;
    if (t < NCELL) {
        const int* hb = hists + (b * SUBS_PER_B) * NCELL + t;
        int acc = 0;
        #pragma unroll
        for (int s2 = 0; s2 < SUBS_PER_B; ++s2) {
            if (s2 == s) mybase = acc;
            acc += hb[s2 * NCELL];
        }
        total = acc;
    }

    // Inclusive Hillis-Steele scan of per-cell totals (threads 0-127 active,
    // barriers unconditional for the whole block).
    if (t < 128) sbuf[t] = (t < NCELL) ? total : 0;
    __syncthreads();
    for (int off = 1; off < 128; off <<= 1) {
        int v = 0;
        if (t < 128 && t >= off) v = sbuf[t - off];
        __syncthreads();
        if (t < 128) sbuf[t] += v;
        __syncthreads();
    }
    if (t < NCELL) {
        const int excl = sbuf[t] - total;          // exclusive cell start
        cursor[t] = excl + mybase;                 // my sub-block's base in cell t
        if (s == 0) {                              // one writer per batch
            cell_start[b * (NCELL + 1) + t + 1] = sbuf[t];
            if (t == 0) cell_start[b * (NCELL + 1)] = 0;
        }
    }
    __syncthreads();

    // Scatter my 256 keys. Within-cell order arbitrary (bitmap restores it).
    const int p = k * 256 + t;                     // global key id
    const float x = key[p * 3 + 0];
    const float y = key[p * 3 + 1];
    const float z = key[p * 3 + 2];
    const int cell = (cell_of(x) * GC + cell_of(y)) * GC + cell_of(z);
    const int pos  = atomicAdd(&cursor[cell], 1);  // LDS, block-local
    float4 v;
    v.x = x; v.y = y; v.z = z; v.w = __int_as_float(p & (N2 - 1));
    sorted[(size_t)b * N2 + pos] = v;
}

// ---------------- per-query grid scan (unchanged from R4) ----------------
__global__ __launch_bounds__(256) void ballquery_grid_kernel(
    const float* __restrict__ query,        // [B*N1, 3]
    const float4* __restrict__ sorted,      // [B*N2] grouped by cell
    const int* __restrict__ cell_start,     // [B, 126]
    int* __restrict__ out)                  // [B*N1, K]
{
    __shared__ unsigned int bm[4 * 256];    // 4 waves x 8192-bit bitmap

    const int lane = threadIdx.x & 63;
    const int wv   = threadIdx.x >> 6;
    const int q    = blockIdx.x * 4 + wv;   // 0 .. B*N1-1
    const int b    = q >> 11;

    const float qx = query[q * 3 + 0];
    const float qy = query[q * 3 + 1];
    const float qz = query[q * 3 + 2];

    // Octant of cells the ball can touch (cell = 2r, so +/-1 on the near side).
    const float ux = qx * INVCELL, uy = qy * INVCELL, uz = qz * INVCELL;
    const int cx = cell_of(qx), cy = cell_of(qy), cz = cell_of(qz);
    const int nx = (ux - cx < 0.5f) ? cx - 1 : cx + 1;
    const int ny = (uy - cy < 0.5f) ? cy - 1 : cy + 1;
    const int nz = (uz - cz < 0.5f) ? cz - 1 : cz + 1;
    const int xlo = max(0, min(cx, nx)), xhi = min(GC - 1, max(cx, nx));
    const int ylo = max(0, min(cy, ny)), yhi = min(GC - 1, max(cy, ny));
    const int zlo = max(0, min(cz, nz)), zhi = min(GC - 1, max(cz, nz));

    unsigned int* wbm = bm + wv * 256;
    uint4 zz; zz.x = zz.y = zz.z = zz.w = 0u;
    ((uint4*)wbm)[lane] = zz;               // clear bitmap (ds_write_b128)
    __threadfence_block();

    const int*    cs = cell_start + b * (NCELL + 1);
    const float4* sb = sorted + (size_t)b * N2;

    for (int xx = xlo; xx <= xhi; ++xx) {
        for (int yy = ylo; yy <= yhi; ++yy) {
            const int colz = (xx * GC + yy) * GC;
            const int s = cs[colz + zlo];
            const int e = cs[colz + zhi + 1];          // z-cells are contiguous
            for (int t0 = s; t0 < e; t0 += 64) {
                const int i = t0 + lane;
                const float4 kv = sb[min(i, e - 1)];
                const float dx = kv.x - qx;
                const float dy = kv.y - qy;
                const float dz = kv.z - qz;
                const bool within = (i < e) && (dx * dx + dy * dy + dz * dz < R2);
                if (within) {
                    const int id = __float_as_int(kv.w);
                    atomicOr(&wbm[id >> 5], 1u << (id & 31));
                }
            }
        }
    }
    __threadfence_block();

    // ---- extraction: lane owns original-index range [128*lane, 128*lane+128)
    const uint4 w = ((const uint4*)wbm)[lane];
    const int c = __popc(w.x) + __popc(w.y) + __popc(w.z) + __popc(w.w);

    // inclusive wave prefix sum of c
    int x = c;
    #pragma unroll
    for (int off = 1; off < 64; off <<= 1) {
        int y = __shfl_up(x, off);
        if (lane >= off) x += y;
    }
    const int base = x - c;
    const int cnt  = __shfl(x, 63);

    // first set bit overall (0 if none)
    int fs;
    if      (w.x) fs = __builtin_ctz(w.x);
    else if (w.y) fs = 32 + __builtin_ctz(w.y);
    else if (w.z) fs = 64 + __builtin_ctz(w.z);
    else if (w.w) fs = 96 + __builtin_ctz(w.w);
    else          fs = 0;
    int myfirst = c ? (lane << 7) + fs : 0x7fffffff;
    #pragma unroll
    for (int off = 32; off; off >>= 1)
        myfirst = min(myfirst, __shfl_xor(myfirst, off));
    const int firstIdx = (cnt == 0) ? 0 : myfirst;

    // emit set bits in order
    int* op = out + q * K;
    int slot = base;
    unsigned int wr[4] = {w.x, w.y, w.z, w.w};
    #pragma unroll
    for (int r = 0; r < 4; ++r) {
        unsigned int m = wr[r];
        const int bb = (lane << 7) + (r << 5);
        while (m) {
            const int bp = __builtin_ctz(m);
            m &= m - 1;
            if (slot < K) op[slot] = bb + bp;
            ++slot;
        }
    }

    // pad remaining slots with firstIdx
    const int kpad = cnt < K ? cnt : K;
    const int s2 = kpad + lane;
    if (s2 < K) op[s2] = firstIdx;
}

// ---------------- fallback (ws too small): brute force ----------------
__global__ __launch_bounds__(256) void ballquery_bruteforce_kernel(
    const float* __restrict__ query, const float* __restrict__ key,
    int* __restrict__ out)
{
    const int lane = threadIdx.x & 63;
    const int q = blockIdx.x * 4 + (threadIdx.x >> 6);
    const int b = q >> 11;
    const float qx = query[q * 3], qy = query[q * 3 + 1], qz = query[q * 3 + 2];
    const float* kb = key + (size_t)b * N2 * 3;
    int* op = out + (size_t)q * K;
    int count = 0, first = 0;
    bool have_first = false;
    const unsigned long long lane_mask_lt = (lane == 0) ? 0ull : (~0ull >> (64 - lane));
    for (int c = 0; c < N2 / 64; ++c) {
        if (count >= K) break;
        const int j = (c << 6) + lane;
        const float* kp = kb + j * 3;
        const float dx = kp[0] - qx, dy = kp[1] - qy, dz = kp[2] - qz;
        const bool within = dx * dx + dy * dy + dz * dz < R2;
        const unsigned long long mask = __ballot(within);
        if (mask) {
            if (!have_first) { first = (c << 6) + __builtin_ctzll(mask); have_first = true; }
            if (within) {
                const int slot = count + __popcll(mask & lane_mask_lt);
                if (slot < K) op[slot] = j;
            }
            count += __popcll(mask);
        }
    }
    const int cnt = count < K ? count : K;
    if (cnt + lane < K) op[cnt + lane] = first;
}

extern "C" void kernel_launch(void* const* d_in, const int* in_sizes, int n_in,
                              void* d_out, int out_size, void* d_ws, size_t ws_size,
                              hipStream_t stream) {
    const float* query = (const float*)d_in[0];   // B*N1*3 floats
    const float* key   = (const float*)d_in[1];   // B*N2*3 floats
    int* out = (int*)d_out;                       // B*N1*K int32

    if (ws_size < WS_NEEDED) {
        ballquery_bruteforce_kernel<<<(B * N1) / 4, 256, 0, stream>>>(query, key, out);
        return;
    }

    float4* sorted     = (float4*)d_ws;
    int*    cell_start = (int*)((char*)d_ws + SORTED_BYTES);
    int*    hists      = (int*)((char*)d_ws + SORTED_BYTES + CS_BYTES);

    hist_kernel<<<SUBS, 256, 0, stream>>>(key, hists);
    scatter_kernel<<<SUBS, 256, 0, stream>>>(key, hists, cell_start, sorted);
    ballquery_grid_kernel<<<(B * N1) / 4, 256, 0, stream>>>(query, sorted, cell_start, out);
}